// Round 1
// baseline (12683.947 us; speedup 1.0000x reference)
//
#include <hip/hip_runtime.h>
#include <hip/hip_cooperative_groups.h>

namespace cg = cooperative_groups;

#define SEQ   512
#define BATCH 64
#define DIM   512
#define NB    128

typedef float  f32x4 __attribute__((ext_vector_type(4)));
typedef short  s16x8 __attribute__((ext_vector_type(8)));

__device__ __forceinline__ float bits2f(unsigned u) {
  union { unsigned u; float f; } v; v.u = u; return v.f;
}
__device__ __forceinline__ float bf2f(unsigned short h) { return bits2f((unsigned)h << 16); }
__device__ __forceinline__ float bflo(unsigned u) { return bits2f(u << 16); }
__device__ __forceinline__ float bfhi(unsigned u) { return bits2f(u & 0xFFFF0000u); }
__device__ __forceinline__ unsigned short f2bf(float f) {
  union { float f; unsigned u; } v; v.f = f;
  unsigned r = v.u + 0x7FFFu + ((v.u >> 16) & 1u);
  return (unsigned short)(r >> 16);
}
__device__ __forceinline__ float sigm(float x) { return 1.0f / (1.0f + __expf(-x)); }

// ---------------------------------------------------------------------------
// Kernel 1: cast/pack weights.
//  mode 0: fp32 -> bf16 plain
//  mode 1: fp32 512x512 -> bf16 transposed (WbT[n][k] = W[k][n])
//  mode 2: pack (clock_h << 16) | clock_z into uint per element
// ---------------------------------------------------------------------------
struct CastJobs {
  const float* src[11];
  const float* src2[11];
  void*        dst[11];
  int          n[11];
  int          mode[11];
};

__global__ __launch_bounds__(256) void cast_kernel(CastJobs jobs) {
  int gsz = gridDim.x * blockDim.x;
  int gid = blockIdx.x * blockDim.x + threadIdx.x;
  for (int j = 0; j < 11; ++j) {
    int n = jobs.n[j], mode = jobs.mode[j];
    const float* s = jobs.src[j];
    if (mode == 0) {
      unsigned short* d = (unsigned short*)jobs.dst[j];
      for (int i = gid; i < n; i += gsz) d[i] = f2bf(s[i]);
    } else if (mode == 1) {
      unsigned short* d = (unsigned short*)jobs.dst[j];
      for (int i = gid; i < n; i += gsz) {
        int k = i >> 9, nn = i & 511;
        d[nn * 512 + k] = f2bf(s[i]);
      }
    } else {
      const float* s2 = jobs.src2[j];
      unsigned* d = (unsigned*)jobs.dst[j];
      for (int i = gid; i < n; i += gsz)
        d[i] = ((unsigned)f2bf(s2[i]) << 16) | (unsigned)f2bf(s[i]);
    }
  }
}

// ---------------------------------------------------------------------------
// Kernel 2: projection GEMM (bf16 MFMA).
// C[(t*64+b), n] = sum_k x[b,t,k] * W[k,n] + bias[n], for W in {W, Wr, Wz}.
// Grid: blockIdx.x = t*12 + nt; nt -> (wsel = nt>>2, ncol0 = (nt&3)*128).
// Per WG: C-tile 64(b) x 128(n), K=512 in 16 steps of 32.
// MFMA layouts (HW-verified per guide): A[m=lane&15][k=(lane>>4)*8+j],
// B[k=(lane>>4)*8+j][n=lane&15], D col=lane&15 row=(lane>>4)*4+reg.
// ---------------------------------------------------------------------------
__global__ __launch_bounds__(256) void proj_kernel(
    const float* __restrict__ x,
    const unsigned short* __restrict__ WbT,   // [3][n=512][k=512] bf16
    const float* __restrict__ bias0, const float* __restrict__ bias1,
    const float* __restrict__ bias2,
    unsigned short* __restrict__ p0, unsigned short* __restrict__ p1,
    unsigned short* __restrict__ p2)
{
  __shared__ __align__(16) unsigned short aS[64 * 40];
  __shared__ __align__(16) unsigned short bS[128 * 40];

  int bx = blockIdx.x;
  int nt = bx % 12, t = bx / 12;
  int wsel = nt >> 2, ncol0 = (nt & 3) * 128;
  const float* bias = (wsel == 0) ? bias0 : (wsel == 1 ? bias1 : bias2);
  unsigned short* pout = (wsel == 0) ? p0 : (wsel == 1 ? p1 : p2);

  int tid = threadIdx.x;
  int wv = tid >> 6, lane = tid & 63;
  int lq = lane & 15, quad = lane >> 4;

  f32x4 acc[8];
#pragma unroll
  for (int s = 0; s < 8; ++s) acc[s] = (f32x4){0.f, 0.f, 0.f, 0.f};

  int arow = tid >> 2, ak0 = (tid & 3) * 8;            // 64 rows x 32 k
  const float* asrc0 = x + ((size_t)arow * SEQ + t) * DIM + ak0;
  int brow = tid >> 1, bk0 = (tid & 1) * 16;           // 128 n x 32 k
  const unsigned short* bsrc0 =
      WbT + ((size_t)(wsel * 512 + ncol0 + brow)) * 512 + bk0;

  for (int kk = 0; kk < 16; ++kk) {
    // stage A (fp32 -> bf16)
    const float* asrc = asrc0 + kk * 32;
    float4 f0 = *(const float4*)(asrc);
    float4 f1 = *(const float4*)(asrc + 4);
    uint4 av;
    av.x = (unsigned)f2bf(f0.x) | ((unsigned)f2bf(f0.y) << 16);
    av.y = (unsigned)f2bf(f0.z) | ((unsigned)f2bf(f0.w) << 16);
    av.z = (unsigned)f2bf(f1.x) | ((unsigned)f2bf(f1.y) << 16);
    av.w = (unsigned)f2bf(f1.z) | ((unsigned)f2bf(f1.w) << 16);
    *(uint4*)(aS + arow * 40 + ak0) = av;
    // stage B (already bf16, transposed layout Bt[n][k])
    const unsigned short* bsrc = bsrc0 + kk * 32;
    *(uint4*)(bS + brow * 40 + bk0)     = *(const uint4*)(bsrc);
    *(uint4*)(bS + brow * 40 + bk0 + 8) = *(const uint4*)(bsrc + 8);
    __syncthreads();

    s16x8 af = *(const s16x8*)(aS + (wv * 16 + lq) * 40 + quad * 8);
#pragma unroll
    for (int s = 0; s < 8; ++s) {
      s16x8 bf = *(const s16x8*)(bS + (s * 16 + lq) * 40 + quad * 8);
      acc[s] = __builtin_amdgcn_mfma_f32_16x16x32_bf16(af, bf, acc[s], 0, 0, 0);
    }
    __syncthreads();
  }

#pragma unroll
  for (int s = 0; s < 8; ++s) {
    int col = ncol0 + s * 16 + lq;
    float bv = bias[col];
#pragma unroll
    for (int v = 0; v < 4; ++v) {
      int b = wv * 16 + quad * 4 + v;
      pout[((size_t)(t * BATCH + b)) * DIM + col] = f2bf(acc[s][v] + bv);
    }
  }
}

// ---------------------------------------------------------------------------
// Kernel 3: cooperative scan. 128 WGs x 256 threads.
// WG w: block i = w&3 (m=(i+1)*128, period=1<<i), rows {2*(w>>2), +1}.
// One grid.sync() per timestep; h double-buffered in global.
// Step math (per block i, rows q):
//   r  = sigm(p_r[:, :m] + hp @ Cr_i)      (hp = h[:, :m])
//   u  = r * hp
//   z  = sigm(p_z[:, iN:+128] + hp @ Cz_i)
//   hn = sigm(p_x[:, iN:+128] + u @ Ch_i)
//   v  = z*hn + (1-z)*h[:, iN:+128]   (only when t % period == 0)
// Block 0's Cr lives in LDS (critical path, updates every step); Cz/Ch packed
// per-element in one uint (z lo, h hi) to halve global loads in the z/h loop.
// ---------------------------------------------------------------------------
__global__ __launch_bounds__(256) void scan_kernel(
    const unsigned short* __restrict__ p_x,
    const unsigned short* __restrict__ p_r,
    const unsigned short* __restrict__ p_z,
    const unsigned short* __restrict__ Cr0, const unsigned short* __restrict__ Cr1,
    const unsigned short* __restrict__ Cr2, const unsigned short* __restrict__ Cr3,
    const unsigned* __restrict__ Czh0, const unsigned* __restrict__ Czh1,
    const unsigned* __restrict__ Czh2, const unsigned* __restrict__ Czh3,
    float* __restrict__ hbuf,   // 2 * 64*512 fp32
    float* __restrict__ out)    // (B, SEQ, DIM) fp32
{
  cg::grid_group grid = cg::this_grid();

  __shared__ __align__(16) float hpS[512 * 2];   // [k][q], q = row within pair
  __shared__ __align__(16) float uS[512 * 2];    // [j][q]
  __shared__ __align__(4)  unsigned short crS[128 * 128];  // block-0 Cr cache

  int w = blockIdx.x;
  int i = w & 3, rg = w >> 2;
  int b0 = rg * 2;
  int m = (i + 1) * NB, iN = i * NB, per = 1 << i;
  int tid = threadIdx.x;

  const unsigned short* Cr = (i == 0) ? Cr0 : (i == 1) ? Cr1 : (i == 2) ? Cr2 : Cr3;
  const unsigned* Czh = (i == 0) ? Czh0 : (i == 1) ? Czh1 : (i == 2) ? Czh2 : Czh3;

  if (i == 0)
    for (int idx = tid; idx < 128 * 128; idx += 256) crS[idx] = Cr0[idx];

  float* h0 = hbuf;
  float* h1 = hbuf + BATCH * DIM;
  {  // zero-init this WG's slice of h0
    int q = tid >> 7, j = tid & 127;
    h0[(b0 + q) * DIM + iN + j] = 0.f;
  }
  grid.sync();

  for (int t = 0; t < SEQ; ++t) {
    float* hc = (t & 1) ? h1 : h0;
    float* hn = (t & 1) ? h0 : h1;

    if ((t & (per - 1)) == 0) {
      // ---- load hp (this row-pair's prefix h[:, :m]) into LDS [k][q]
      for (int idx = tid; idx < 2 * m; idx += 256) {
        int q = (idx < m) ? 0 : 1;
        int k = idx - q * m;
        hpS[k * 2 + q] = hc[(b0 + q) * DIM + k];
      }
      __syncthreads();

      // ---- r and u = r*hp : thread owns columns (j2, j2+1) for both rows
      int j2 = tid * 2;
      if (j2 < m) {
        const unsigned short* pr0 = p_r + ((size_t)(t * BATCH + b0)) * DIM;
        const unsigned short* pr1 = pr0 + DIM;
        float a00 = bf2f(pr0[j2]), a01 = bf2f(pr0[j2 + 1]);
        float a10 = bf2f(pr1[j2]), a11 = bf2f(pr1[j2 + 1]);
        if (i == 0) {
          for (int k = 0; k < 128; ++k) {
            unsigned cc = *(const unsigned*)(crS + k * 128 + j2);
            float c0 = bflo(cc), c1 = bfhi(cc);
            float2 h2 = *(const float2*)(hpS + k * 2);
            a00 += h2.x * c0; a01 += h2.x * c1;
            a10 += h2.y * c0; a11 += h2.y * c1;
          }
        } else {
          const unsigned short* crp = Cr + j2;
          for (int k = 0; k < m; ++k) {
            unsigned cc = *(const unsigned*)(crp + (size_t)k * m);
            float c0 = bflo(cc), c1 = bfhi(cc);
            float2 h2 = *(const float2*)(hpS + k * 2);
            a00 += h2.x * c0; a01 += h2.x * c1;
            a10 += h2.y * c0; a11 += h2.y * c1;
          }
        }
        uS[j2 * 2 + 0]       = sigm(a00) * hpS[j2 * 2 + 0];
        uS[(j2 + 1) * 2 + 0] = sigm(a01) * hpS[(j2 + 1) * 2 + 0];
        uS[j2 * 2 + 1]       = sigm(a10) * hpS[j2 * 2 + 1];
        uS[(j2 + 1) * 2 + 1] = sigm(a11) * hpS[(j2 + 1) * 2 + 1];
      }
      __syncthreads();

      // ---- z, h_new, v : thread owns (row q, col j) of the 128-wide block
      {
        int q = tid >> 7, j = tid & 127;
        size_t prow = (size_t)(t * BATCH + b0 + q) * DIM + iN + j;
        float az = bf2f(p_z[prow]);
        float ah = bf2f(p_x[prow]);
        const unsigned* cp = Czh + j;
        for (int k = 0; k < m; ++k) {
          unsigned u = cp[(size_t)k * NB];
          az += hpS[k * 2 + q] * bflo(u);
          ah += uS[k * 2 + q] * bfhi(u);
        }
        float z = sigm(az), hnw = sigm(ah);
        float nah = hpS[(m - NB + j) * 2 + q];
        float v = z * hnw + (1.f - z) * nah;
        hn[(b0 + q) * DIM + iN + j] = v;
        out[(size_t)(b0 + q) * SEQ * DIM + (size_t)t * DIM + iN + j] = v;
      }
    } else {
      // holding step: copy state forward, write output
      int q = tid >> 7, j = tid & 127;
      float v = hc[(b0 + q) * DIM + iN + j];
      hn[(b0 + q) * DIM + iN + j] = v;
      out[(size_t)(b0 + q) * SEQ * DIM + (size_t)t * DIM + iN + j] = v;
    }
    grid.sync();
  }
}

// ---------------------------------------------------------------------------
// Host launcher
// ---------------------------------------------------------------------------
extern "C" void kernel_launch(void* const* d_in, const int* in_sizes, int n_in,
                              void* d_out, int out_size, void* d_ws, size_t ws_size,
                              hipStream_t stream) {
  (void)in_sizes; (void)n_in; (void)out_size; (void)ws_size;

  const float* x  = (const float*)d_in[0];
  const float* W  = (const float*)d_in[1];
  const float* bb = (const float*)d_in[2];
  const float* Wr = (const float*)d_in[3];
  const float* br = (const float*)d_in[4];
  const float* Wz = (const float*)d_in[5];
  const float* bz = (const float*)d_in[6];
  const float* ch_[4]; const float* cr_[4]; const float* cz_[4];
  for (int i = 0; i < 4; ++i) {
    ch_[i] = (const float*)d_in[7 + 3 * i];
    cr_[i] = (const float*)d_in[8 + 3 * i];
    cz_[i] = (const float*)d_in[9 + 3 * i];
  }

  // workspace layout (bytes)
  char* ws = (char*)d_ws;
  const size_t crElems[4]  = {16384, 65536, 147456, 262144};   // m*m
  const size_t czhElems[4] = {16384, 32768, 49152, 65536};     // m*128

  size_t off = 0;
  unsigned short* WbT = (unsigned short*)(ws + off); off += 3ull * 512 * 512 * 2;
  unsigned short* Crb[4];
  for (int i = 0; i < 4; ++i) { Crb[i] = (unsigned short*)(ws + off); off += crElems[i] * 2; }
  unsigned* Czh[4];
  for (int i = 0; i < 4; ++i) { Czh[i] = (unsigned*)(ws + off); off += czhElems[i] * 4; }
  unsigned short* p0 = (unsigned short*)(ws + off); off += (size_t)SEQ * BATCH * DIM * 2;
  unsigned short* p1 = (unsigned short*)(ws + off); off += (size_t)SEQ * BATCH * DIM * 2;
  unsigned short* p2 = (unsigned short*)(ws + off); off += (size_t)SEQ * BATCH * DIM * 2;
  float* hbuf = (float*)(ws + off); off += 2ull * BATCH * DIM * 4;
  // total ~104.1 MB

  // ---- cast/pack weights
  CastJobs jobs;
  const float* wsrc[3] = {W, Wr, Wz};
  for (int j = 0; j < 3; ++j) {
    jobs.src[j] = wsrc[j]; jobs.src2[j] = nullptr;
    jobs.dst[j] = WbT + (size_t)j * 512 * 512;
    jobs.n[j] = 512 * 512; jobs.mode[j] = 1;
  }
  for (int i = 0; i < 4; ++i) {
    jobs.src[3 + i] = cr_[i]; jobs.src2[3 + i] = nullptr;
    jobs.dst[3 + i] = Crb[i]; jobs.n[3 + i] = (int)crElems[i]; jobs.mode[3 + i] = 0;
  }
  for (int i = 0; i < 4; ++i) {
    jobs.src[7 + i] = cz_[i]; jobs.src2[7 + i] = ch_[i];
    jobs.dst[7 + i] = Czh[i]; jobs.n[7 + i] = (int)czhElems[i]; jobs.mode[7 + i] = 2;
  }
  cast_kernel<<<256, 256, 0, stream>>>(jobs);

  // ---- projections
  proj_kernel<<<SEQ * 12, 256, 0, stream>>>(x, WbT, bb, br, bz, p0, p1, p2);

  // ---- cooperative scan
  float* outp = (float*)d_out;
  const unsigned short* a_px = p0; const unsigned short* a_pr = p1;
  const unsigned short* a_pz = p2;
  const unsigned short* a_cr0 = Crb[0]; const unsigned short* a_cr1 = Crb[1];
  const unsigned short* a_cr2 = Crb[2]; const unsigned short* a_cr3 = Crb[3];
  const unsigned* a_cz0 = Czh[0]; const unsigned* a_cz1 = Czh[1];
  const unsigned* a_cz2 = Czh[2]; const unsigned* a_cz3 = Czh[3];
  float* a_hbuf = hbuf;
  void* args[] = {
    (void*)&a_px, (void*)&a_pr, (void*)&a_pz,
    (void*)&a_cr0, (void*)&a_cr1, (void*)&a_cr2, (void*)&a_cr3,
    (void*)&a_cz0, (void*)&a_cz1, (void*)&a_cz2, (void*)&a_cz3,
    (void*)&a_hbuf, (void*)&outp
  };
  hipLaunchCooperativeKernel((void*)scan_kernel, dim3(128), dim3(256),
                             args, 0, stream);
}

// Round 2
// 1895.471 us; speedup vs baseline: 6.6917x; 6.6917x over previous
//
#include <hip/hip_runtime.h>

#define SEQ   512
#define BATCH 64
#define DIM   512

typedef float  f32x4 __attribute__((ext_vector_type(4)));
typedef short  s16x8 __attribute__((ext_vector_type(8)));
typedef __bf16 bf16x2 __attribute__((ext_vector_type(2)));

__device__ __forceinline__ float bits2f(unsigned u) {
  union { unsigned u; float f; } v; v.u = u; return v.f;
}
__device__ __forceinline__ float bf2f(unsigned short h) { return bits2f((unsigned)h << 16); }
__device__ __forceinline__ float bflo(unsigned u) { return bits2f(u << 16); }
__device__ __forceinline__ float bfhi(unsigned u) { return bits2f(u & 0xFFFF0000u); }
__device__ __forceinline__ unsigned short f2bf(float f) {
  union { float f; unsigned u; } v; v.f = f;
  unsigned r = v.u + 0x7FFFu + ((v.u >> 16) & 1u);
  return (unsigned short)(r >> 16);
}
__device__ __forceinline__ unsigned packbf(float lo, float hi) {
  return (unsigned)f2bf(lo) | ((unsigned)f2bf(hi) << 16);
}
__device__ __forceinline__ float sigm(float x) { return 1.0f / (1.0f + __expf(-x)); }

// dot of two bf16 pairs accumulated into f32.  w/h pair layout: lo16 = even k,
// hi16 = odd k.
__device__ __forceinline__ float dot2(unsigned w, unsigned h, float acc) {
#if __has_builtin(__builtin_amdgcn_fdot2_f32_bf16)
  return __builtin_amdgcn_fdot2_f32_bf16(__builtin_bit_cast(bf16x2, w),
                                         __builtin_bit_cast(bf16x2, h), acc, false);
#else
  return acc + bflo(w) * bflo(h) + bfhi(w) * bfhi(h);
#endif
}

// ---------------------------------------------------------------------------
// Kernel 1: cast/pack weights.
//  mode 1: fp32 512x512 -> bf16 transposed  (WbT[n][k] = W[k][n])
//  mode 3: Crpk:  [k2<64][j<m]   = pack(Cr[iN+2k2][j],  Cr[iN+2k2+1][j])
//  mode 4: Chpk:  [k2<m/2][j<128]= pack(Ch[2k2][j],     Ch[2k2+1][j])
//  mode 5: Czpk:  [k2<64][j<128] = pack(Cz[iN+2k2][j],  Cz[iN+2k2+1][j])
//  mode 6: Bcat:  bf16 [nrow<m+128][k<iN]: nrow<m -> Cr[k][nrow], else Cz[k][nrow-m]
// ---------------------------------------------------------------------------
#define NJOBS 18
struct CastJobs {
  const float* src[NJOBS];
  const float* src2[NJOBS];
  void*        dst[NJOBS];
  int          n[NJOBS];
  int          mode[NJOBS];
  int          m[NJOBS];
  int          iN[NJOBS];
};

__global__ __launch_bounds__(256) void cast_kernel(CastJobs jobs) {
  int gsz = gridDim.x * blockDim.x;
  int gid = blockIdx.x * blockDim.x + threadIdx.x;
  for (int j = 0; j < NJOBS; ++j) {
    int n = jobs.n[j], mode = jobs.mode[j];
    int m = jobs.m[j], iN = jobs.iN[j];
    const float* s = jobs.src[j];
    if (mode == 1) {
      unsigned short* d = (unsigned short*)jobs.dst[j];
      for (int i = gid; i < n; i += gsz) {
        int k = i >> 9, nn = i & 511;
        d[nn * 512 + k] = f2bf(s[i]);
      }
    } else if (mode == 3) {
      unsigned* d = (unsigned*)jobs.dst[j];
      for (int i = gid; i < n; i += gsz) {
        int k2 = i / m, jj = i - k2 * m;
        d[i] = packbf(s[(iN + 2 * k2) * m + jj], s[(iN + 2 * k2 + 1) * m + jj]);
      }
    } else if (mode == 4) {
      unsigned* d = (unsigned*)jobs.dst[j];
      for (int i = gid; i < n; i += gsz) {
        int k2 = i >> 7, jj = i & 127;
        d[i] = packbf(s[(2 * k2) * 128 + jj], s[(2 * k2 + 1) * 128 + jj]);
      }
    } else if (mode == 5) {
      unsigned* d = (unsigned*)jobs.dst[j];
      for (int i = gid; i < n; i += gsz) {
        int k2 = i >> 7, jj = i & 127;
        d[i] = packbf(s[(iN + 2 * k2) * 128 + jj], s[(iN + 2 * k2 + 1) * 128 + jj]);
      }
    } else if (mode == 6) {
      const float* s2 = jobs.src2[j];
      unsigned short* d = (unsigned short*)jobs.dst[j];
      for (int i = gid; i < n; i += gsz) {
        int nrow = i / iN, k = i - nrow * iN;
        float v = (nrow < m) ? s[k * m + nrow] : s2[k * 128 + (nrow - m)];
        d[i] = f2bf(v);
      }
    }
  }
}

// ---------------------------------------------------------------------------
// Kernel 2: projection GEMM (bf16 MFMA) — validated in R1.
// ---------------------------------------------------------------------------
__global__ __launch_bounds__(256) void proj_kernel(
    const float* __restrict__ x,
    const unsigned short* __restrict__ WbT,
    const float* __restrict__ bias0, const float* __restrict__ bias1,
    const float* __restrict__ bias2,
    unsigned short* __restrict__ p0, unsigned short* __restrict__ p1,
    unsigned short* __restrict__ p2)
{
  __shared__ __align__(16) unsigned short aS[64 * 40];
  __shared__ __align__(16) unsigned short bS[128 * 40];

  int bx = blockIdx.x;
  int nt = bx % 12, t = bx / 12;
  int wsel = nt >> 2, ncol0 = (nt & 3) * 128;
  const float* bias = (wsel == 0) ? bias0 : (wsel == 1 ? bias1 : bias2);
  unsigned short* pout = (wsel == 0) ? p0 : (wsel == 1 ? p1 : p2);

  int tid = threadIdx.x;
  int wv = tid >> 6, lane = tid & 63;
  int lq = lane & 15, quad = lane >> 4;

  f32x4 acc[8];
#pragma unroll
  for (int s = 0; s < 8; ++s) acc[s] = (f32x4){0.f, 0.f, 0.f, 0.f};

  int arow = tid >> 2, ak0 = (tid & 3) * 8;
  const float* asrc0 = x + ((size_t)arow * SEQ + t) * DIM + ak0;
  int brow = tid >> 1, bk0 = (tid & 1) * 16;
  const unsigned short* bsrc0 =
      WbT + ((size_t)(wsel * 512 + ncol0 + brow)) * 512 + bk0;

  for (int kk = 0; kk < 16; ++kk) {
    const float* asrc = asrc0 + kk * 32;
    float4 f0 = *(const float4*)(asrc);
    float4 f1 = *(const float4*)(asrc + 4);
    uint4 av;
    av.x = packbf(f0.x, f0.y);
    av.y = packbf(f0.z, f0.w);
    av.z = packbf(f1.x, f1.y);
    av.w = packbf(f1.z, f1.w);
    *(uint4*)(aS + arow * 40 + ak0) = av;
    const unsigned short* bsrc = bsrc0 + kk * 32;
    *(uint4*)(bS + brow * 40 + bk0)     = *(const uint4*)(bsrc);
    *(uint4*)(bS + brow * 40 + bk0 + 8) = *(const uint4*)(bsrc + 8);
    __syncthreads();

    s16x8 af = *(const s16x8*)(aS + (wv * 16 + lq) * 40 + quad * 8);
#pragma unroll
    for (int s = 0; s < 8; ++s) {
      s16x8 bf = *(const s16x8*)(bS + (s * 16 + lq) * 40 + quad * 8);
      acc[s] = __builtin_amdgcn_mfma_f32_16x16x32_bf16(af, bf, acc[s], 0, 0, 0);
    }
    __syncthreads();
  }

#pragma unroll
  for (int s = 0; s < 8; ++s) {
    int col = ncol0 + s * 16 + lq;
    float bv = bias[col];
#pragma unroll
    for (int v = 0; v < 4; ++v) {
      int b = wv * 16 + quad * 4 + v;
      pout[((size_t)(t * BATCH + b)) * DIM + col] = f2bf(acc[s][v] + bv);
    }
  }
}

// ---------------------------------------------------------------------------
// Kernel 3: base GEMM for block I (I=1..3):
// base[(n*64+b)][c] = sum_{k<iN} out[b][n*2^I - 1][k] * Bcat[c][k]   (bf16 out)
// where Bcat rows: c<m -> Cr_I[:,c], c>=m -> Cz_I[:,c-m].  n=0 rows -> 0.
// ---------------------------------------------------------------------------
template<int I>
__global__ __launch_bounds__(256) void base_gemm(
    const float* __restrict__ outp,
    const unsigned short* __restrict__ Bcat,
    unsigned short* __restrict__ baseO)
{
  constexpr int KI  = 4 * I;      // K/32
  constexpr int K   = 128 * I;    // = iN
  constexpr int NT  = I + 2;      // n-tiles of 128
  constexpr int NW  = NT * 128;   // m + 128
  constexpr int PER = 1 << I;

  __shared__ __align__(16) unsigned short aS[64 * 40];
  __shared__ __align__(16) unsigned short bS[128 * 40];

  int bx = blockIdx.x;
  int nt = bx % NT, n = bx / NT;
  int ncol0 = nt * 128;

  int tid = threadIdx.x;
  int wv = tid >> 6, lane = tid & 63;
  int lq = lane & 15, quad = lane >> 4;

  f32x4 acc[8];
#pragma unroll
  for (int s = 0; s < 8; ++s) acc[s] = (f32x4){0.f, 0.f, 0.f, 0.f};

  int arow = tid >> 2, ak0 = (tid & 3) * 8;
  const float* asrc0 = outp + ((size_t)arow * SEQ + (n * PER - 1)) * DIM + ak0;
  int brow = tid >> 1, bk0 = (tid & 1) * 16;
  const unsigned short* bsrc0 = Bcat + (size_t)(ncol0 + brow) * K + bk0;

  for (int kk = 0; kk < KI; ++kk) {
    uint4 av;
    if (n > 0) {
      const float* asrc = asrc0 + kk * 32;
      float4 f0 = *(const float4*)(asrc);
      float4 f1 = *(const float4*)(asrc + 4);
      av.x = packbf(f0.x, f0.y);
      av.y = packbf(f0.z, f0.w);
      av.z = packbf(f1.x, f1.y);
      av.w = packbf(f1.z, f1.w);
    } else {
      av = (uint4){0u, 0u, 0u, 0u};
    }
    *(uint4*)(aS + arow * 40 + ak0) = av;
    const unsigned short* bsrc = bsrc0 + kk * 32;
    *(uint4*)(bS + brow * 40 + bk0)     = *(const uint4*)(bsrc);
    *(uint4*)(bS + brow * 40 + bk0 + 8) = *(const uint4*)(bsrc + 8);
    __syncthreads();

    s16x8 af = *(const s16x8*)(aS + (wv * 16 + lq) * 40 + quad * 8);
#pragma unroll
    for (int s = 0; s < 8; ++s) {
      s16x8 bf = *(const s16x8*)(bS + (s * 16 + lq) * 40 + quad * 8);
      acc[s] = __builtin_amdgcn_mfma_f32_16x16x32_bf16(af, bf, acc[s], 0, 0, 0);
    }
    __syncthreads();
  }

#pragma unroll
  for (int s = 0; s < 8; ++s) {
    int col = ncol0 + s * 16 + lq;
#pragma unroll
    for (int v = 0; v < 4; ++v) {
      int bb = wv * 16 + quad * 4 + v;
      baseO[(size_t)(n * 64 + bb) * NW + col] = f2bf(acc[s][v]);
    }
  }
}

// ---------------------------------------------------------------------------
// Kernel 4: per-block scan phase. 64 WGs (one batch row each) x 256 threads.
// Weights in VGPRs (packed bf16 k-pairs), own 128-state in LDS, no grid sync.
// Segments per update:
//   seg1: r (all r-cols; I==0: z concurrently on thr>=128) -> uF
//   seg2: z (thr>=128, I>=1) + pack uF -> uPk (thr<128)
//   seg3: h-matmul (2-way k-split) -> reduce -> finalize, write hS/hPk/out
// ---------------------------------------------------------------------------
template<int I>
__global__ __launch_bounds__(256, 1) void scan_phase(
    const unsigned short* __restrict__ px,
    const unsigned short* __restrict__ pr,
    const unsigned short* __restrict__ pz,
    const unsigned* __restrict__ crpk,
    const unsigned* __restrict__ czpk,
    const unsigned* __restrict__ chpk,
    const unsigned short* __restrict__ base,
    float* __restrict__ out)
{
  constexpr int M   = (I + 1) * 128;
  constexpr int IN  = I * 128;
  constexpr int PER = 1 << I;
  constexpr int U   = 512 >> I;
  constexpr int NW  = M + 128;
  constexpr int HKP = M / 2;      // u k-pairs
  constexpr int HT  = HKP / 2;    // per-thread h k-pairs (2-way split)

  __shared__ float    hS[128];
  __shared__ unsigned hPk[64];
  __shared__ float    uF[M];
  __shared__ unsigned uPk[HKP];
  __shared__ float    zS[128];
  __shared__ float    part[128];

  const int b = blockIdx.x;
  const int t = threadIdx.x;
  const int jh = t & 127, qh = t >> 7;

  constexpr bool R0ALL = (M >= 256);
  const int  col0  = t;
  const bool hasR0 = R0ALL || (t < 128);
  const int  col1  = 256 + t;
  const bool hasR1 = (I >= 2) && (col1 < M);
  const bool isZ   = (t >= 128);
  const int  jz    = t - 128;

  // ---- weights -> registers
  unsigned wr0[64];
  if (hasR0) {
#pragma unroll
    for (int k2 = 0; k2 < 64; ++k2) wr0[k2] = crpk[k2 * M + col0];
  }
  unsigned wr1[(I >= 2) ? 64 : 1];
  if constexpr (I >= 2) {
    if (hasR1) {
#pragma unroll
      for (int k2 = 0; k2 < 64; ++k2) wr1[k2] = crpk[k2 * M + col1];
    }
  }
  unsigned wz[64];
  if (isZ) {
#pragma unroll
    for (int k2 = 0; k2 < 64; ++k2) wz[k2] = czpk[k2 * 128 + jz];
  }
  unsigned wh[HT];
#pragma unroll
  for (int k2 = 0; k2 < HT; ++k2) wh[k2] = chpk[(qh * HT + k2) * 128 + jh];

  if (t < 128) hS[t] = 0.f;
  if (t < 64)  hPk[t] = 0u;
  __syncthreads();

  for (int n = 0; n < U; ++n) {
    const int s = n * PER;
    const unsigned short* prRow = pr + ((size_t)(s * BATCH + b)) * DIM;
    const unsigned short* pzRow = pz + ((size_t)(s * BATCH + b)) * DIM;
    const unsigned short* pxRow = px + ((size_t)(s * BATCH + b)) * DIM;
    const unsigned short* baseRow =
        (I > 0) ? base + (size_t)(n * 64 + b) * NW : (const unsigned short*)nullptr;
    const float* prev = out + ((size_t)b * SEQ + (s - 1)) * DIM;  // valid n>0

    // ---------------- seg1: r (+ z for I==0) ----------------
    if (hasR0) {
      float a0 = 0.f, a0b = 0.f, a1 = 0.f, a1b = 0.f;
#pragma unroll
      for (int k2 = 0; k2 < 64; k2 += 2) {
        unsigned h0 = hPk[k2], h1 = hPk[k2 + 1];
        a0  = dot2(wr0[k2],     h0, a0);
        a0b = dot2(wr0[k2 + 1], h1, a0b);
        if constexpr (I >= 2) {
          if (hasR1) {
            a1  = dot2(wr1[k2],     h0, a1);
            a1b = dot2(wr1[k2 + 1], h1, a1b);
          }
        }
      }
      float ar0 = bf2f(prRow[col0]) + a0 + a0b;
      if constexpr (I > 0) ar0 += bf2f(baseRow[col0]);
      float r0  = sigm(ar0);
      float hp0 = (col0 >= IN) ? hS[col0 - IN] : (n > 0 ? prev[col0] : 0.f);
      uF[col0] = r0 * hp0;
      if constexpr (I >= 2) {
        if (hasR1) {
          float ar1 = bf2f(prRow[col1]) + bf2f(baseRow[col1]) + a1 + a1b;
          float r1  = sigm(ar1);
          float hp1 = (col1 >= IN) ? hS[col1 - IN] : (n > 0 ? prev[col1] : 0.f);
          uF[col1] = r1 * hp1;
        }
      }
    }
    if constexpr (I == 0) {
      if (isZ) {
        float az0 = 0.f, az1 = 0.f;
#pragma unroll
        for (int k2 = 0; k2 < 64; k2 += 2) {
          az0 = dot2(wz[k2],     hPk[k2],     az0);
          az1 = dot2(wz[k2 + 1], hPk[k2 + 1], az1);
        }
        zS[jz] = sigm(bf2f(pzRow[IN + jz]) + az0 + az1);
      }
    }
    __syncthreads();  // A: uF (and zS for I==0) ready

    // ---------------- seg2: z (I>=1) + pack u ----------------
    if constexpr (I >= 1) {
      if (isZ) {
        float az0 = 0.f, az1 = 0.f;
#pragma unroll
        for (int k2 = 0; k2 < 64; k2 += 2) {
          az0 = dot2(wz[k2],     hPk[k2],     az0);
          az1 = dot2(wz[k2 + 1], hPk[k2 + 1], az1);
        }
        zS[jz] = sigm(bf2f(pzRow[IN + jz]) + bf2f(baseRow[M + jz]) + az0 + az1);
      } else {
        int p = t;
        if (p < HKP) uPk[p] = packbf(uF[2 * p], uF[2 * p + 1]);
        if constexpr (HKP > 128) {
          int p2 = t + 128;
          if (p2 < HKP) uPk[p2] = packbf(uF[2 * p2], uF[2 * p2 + 1]);
        }
      }
    } else {
      if (t < HKP) uPk[t] = packbf(uF[2 * t], uF[2 * t + 1]);
    }
    __syncthreads();  // B: uPk, zS ready

    // ---------------- seg3: h-matmul + finalize ----------------
    float ah0 = 0.f, ah1 = 0.f;
    {
      const unsigned* up = uPk + qh * HT;
#pragma unroll
      for (int k2 = 0; k2 < HT; k2 += 2) {
        ah0 = dot2(wh[k2],     up[k2],     ah0);
        ah1 = dot2(wh[k2 + 1], up[k2 + 1], ah1);
      }
    }
    float ah = ah0 + ah1;
    if (qh) part[jh] = ah;
    __syncthreads();  // C: partials ready
    if (!qh) {
      float tot  = ah + part[jh] + bf2f(pxRow[IN + jh]);
      float hnew = sigm(tot);
      float z    = zS[jh];
      float hold = hS[jh];
      float v    = z * hnew + (1.f - z) * hold;
      hS[jh] = v;
      float vo = __shfl_xor(v, 1);
      if (!(t & 1)) hPk[t >> 1] = packbf(v, vo);
      float* orow = out + ((size_t)b * SEQ + s) * DIM + IN + jh;
#pragma unroll
      for (int p = 0; p < PER; ++p) orow[p * DIM] = v;
    }
    __syncthreads();  // E: hS/hPk ready for next update
  }
}

// ---------------------------------------------------------------------------
// Host launcher
// ---------------------------------------------------------------------------
extern "C" void kernel_launch(void* const* d_in, const int* in_sizes, int n_in,
                              void* d_out, int out_size, void* d_ws, size_t ws_size,
                              hipStream_t stream) {
  (void)in_sizes; (void)n_in; (void)out_size; (void)ws_size;

  const float* x  = (const float*)d_in[0];
  const float* W  = (const float*)d_in[1];
  const float* bb = (const float*)d_in[2];
  const float* Wr = (const float*)d_in[3];
  const float* br = (const float*)d_in[4];
  const float* Wz = (const float*)d_in[5];
  const float* bz = (const float*)d_in[6];
  const float* ch_[4]; const float* cr_[4]; const float* cz_[4];
  for (int i = 0; i < 4; ++i) {
    ch_[i] = (const float*)d_in[7 + 3 * i];
    cr_[i] = (const float*)d_in[8 + 3 * i];
    cz_[i] = (const float*)d_in[9 + 3 * i];
  }

  char* ws = (char*)d_ws;
  size_t off = 0;
  auto alloc = [&](size_t bytes) -> void* {
    void* p = ws + off;
    off += (bytes + 255) & ~(size_t)255;
    return p;
  };

  unsigned short* WbT = (unsigned short*)alloc(3ull * 512 * 512 * 2);
  unsigned* Crpk[4]; unsigned* Chpk[4]; unsigned* Czpk[4];
  unsigned short* Bcat[4] = {nullptr, nullptr, nullptr, nullptr};
  for (int i = 0; i < 4; ++i) {
    int m = (i + 1) * 128;
    Crpk[i] = (unsigned*)alloc((size_t)64 * m * 4);
    Chpk[i] = (unsigned*)alloc((size_t)(m / 2) * 128 * 4);
    Czpk[i] = (unsigned*)alloc((size_t)64 * 128 * 4);
  }
  for (int i = 1; i < 4; ++i) {
    int m = (i + 1) * 128, iN = i * 128;
    Bcat[i] = (unsigned short*)alloc((size_t)(m + 128) * iN * 2);
  }
  unsigned short* p0 = (unsigned short*)alloc((size_t)SEQ * BATCH * DIM * 2);
  unsigned short* p1 = (unsigned short*)alloc((size_t)SEQ * BATCH * DIM * 2);
  unsigned short* p2 = (unsigned short*)alloc((size_t)SEQ * BATCH * DIM * 2);
  unsigned short* baseB = (unsigned short*)alloc((size_t)16384 * 384 * 2);  // max of G1..G3
  // total ~117 MB

  // ---- cast/pack jobs
  CastJobs jobs{};
  int jn = 0;
  const float* wsrc[3] = {W, Wr, Wz};
  for (int j = 0; j < 3; ++j) {
    jobs.src[jn] = wsrc[j]; jobs.dst[jn] = WbT + (size_t)j * 512 * 512;
    jobs.n[jn] = 512 * 512; jobs.mode[jn] = 1; jobs.m[jn] = 512; jobs.iN[jn] = 0; jn++;
  }
  for (int i = 0; i < 4; ++i) {
    int m = (i + 1) * 128, iN = i * 128;
    jobs.src[jn] = cr_[i]; jobs.dst[jn] = Crpk[i];
    jobs.n[jn] = 64 * m; jobs.mode[jn] = 3; jobs.m[jn] = m; jobs.iN[jn] = iN; jn++;
    jobs.src[jn] = ch_[i]; jobs.dst[jn] = Chpk[i];
    jobs.n[jn] = (m / 2) * 128; jobs.mode[jn] = 4; jobs.m[jn] = m; jobs.iN[jn] = iN; jn++;
    jobs.src[jn] = cz_[i]; jobs.dst[jn] = Czpk[i];
    jobs.n[jn] = 64 * 128; jobs.mode[jn] = 5; jobs.m[jn] = m; jobs.iN[jn] = iN; jn++;
  }
  for (int i = 1; i < 4; ++i) {
    int m = (i + 1) * 128, iN = i * 128;
    jobs.src[jn] = cr_[i]; jobs.src2[jn] = cz_[i]; jobs.dst[jn] = Bcat[i];
    jobs.n[jn] = (m + 128) * iN; jobs.mode[jn] = 6; jobs.m[jn] = m; jobs.iN[jn] = iN; jn++;
  }
  cast_kernel<<<256, 256, 0, stream>>>(jobs);

  // ---- projections
  proj_kernel<<<SEQ * 12, 256, 0, stream>>>(x, WbT, bb, br, bz, p0, p1, p2);

  float* outp = (float*)d_out;

  // ---- cascade: B0 -> G1 -> B1 -> G2 -> B2 -> G3 -> B3
  scan_phase<0><<<64, 256, 0, stream>>>(p0, p1, p2, Crpk[0], Czpk[0], Chpk[0],
                                        nullptr, outp);
  base_gemm<1><<<256 * 3, 256, 0, stream>>>(outp, Bcat[1], baseB);
  scan_phase<1><<<64, 256, 0, stream>>>(p0, p1, p2, Crpk[1], Czpk[1], Chpk[1],
                                        baseB, outp);
  base_gemm<2><<<128 * 4, 256, 0, stream>>>(outp, Bcat[2], baseB);
  scan_phase<2><<<64, 256, 0, stream>>>(p0, p1, p2, Crpk[2], Czpk[2], Chpk[2],
                                        baseB, outp);
  base_gemm<3><<<64 * 5, 256, 0, stream>>>(outp, Bcat[3], baseB);
  scan_phase<3><<<64, 256, 0, stream>>>(p0, p1, p2, Crpk[3], Czpk[3], Chpk[3],
                                        baseB, outp);
}